// Round 5
// baseline (570.469 us; speedup 1.0000x reference)
//
#include <hip/hip_runtime.h>

// ScaledDotProductAttention: context = softmax(relu(Q K^T) @ R / 8) @ V
// B=8, N=2048, D=64. R = (1+e)/(1+exp(1-dist)), shared across batch.
//
// ws layout (needs >= 83 MB):
//   [0,   64MB)  Ph  : fp16 relu(QK^T)*0.125, [B][N][N]
//   [64MB,72MB)  RhT : fp16 R^T, [j][m]
//   [72MB,74MB)  VhT : fp16 V^T, [B][64][N]
//   [74MB,82MB)  Op  : fp32 partial O, [512 wg][64][64]
//   [82MB,+128K) mp  : fp32 partial rowmax, [512][64]
//   [..,  +128K) lp  : fp32 partial rowsum, [512][64]

typedef _Float16 f16;
typedef _Float16 f16x8 __attribute__((ext_vector_type(8)));
typedef float    f32x4 __attribute__((ext_vector_type(4)));

__device__ __forceinline__ f16x8 cvt_f16x8(float4 a, float4 b){
  f16x8 v;
  v[0]=(f16)a.x; v[1]=(f16)a.y; v[2]=(f16)a.z; v[3]=(f16)a.w;
  v[4]=(f16)b.x; v[5]=(f16)b.y; v[6]=(f16)b.z; v[7]=(f16)b.w;
  return v;
}

// ---------------- kernel 0a: RhT[j][m] = rescale(dist[m][j]) in fp16 -------
__global__ void k_rescaleT(const float* __restrict__ Dm, f16* __restrict__ RhT){
  __shared__ f16 tl[64][65];
  const int k0 = blockIdx.x*64, m0 = blockIdx.y*64;
  const int t = threadIdx.x, c = t & 63, g = t >> 6;
#pragma unroll
  for (int i=0;i<16;++i){
    int k = g*16 + i;
    float d = Dm[(size_t)(k0 + k)*2048 + m0 + c];
    tl[k][c] = (f16)(3.7182818284590452f / (1.0f + __expf(1.0f - d)));
  }
  __syncthreads();
#pragma unroll
  for (int i=0;i<16;++i){
    int m = g*16 + i;
    RhT[(size_t)(m0 + m)*2048 + k0 + c] = tl[c][m];
  }
}

// ---------------- kernel 0b: VhT[b][d][m] = V[b][m][d] in fp16 -------------
__global__ void k_vT(const float* __restrict__ V, f16* __restrict__ VhT){
  __shared__ f16 tl[64][65];
  const int b = blockIdx.y, m0 = blockIdx.x*64;
  const int t = threadIdx.x, c = t & 63, g = t >> 6;
#pragma unroll
  for (int i=0;i<16;++i){
    int m = g*16 + i;
    tl[m][c] = (f16)V[((size_t)b*2048 + m0 + m)*64 + c];
  }
  __syncthreads();
#pragma unroll
  for (int i=0;i<16;++i){
    int d = g*16 + i;
    VhT[((size_t)b*64 + d)*2048 + m0 + c] = tl[c][d];
  }
}

// ---------------- kernel 1: Ph = relu(Q K^T) * 0.125 in fp16 ---------------
__launch_bounds__(256, 2)
__global__ void k_qk(const float* __restrict__ Q, const float* __restrict__ Km,
                     f16* __restrict__ Ph){
  __shared__ char shm[36864];
  f16* Qt = (f16*)shm;            // [128][72]
  f16* Kt = (f16*)(shm + 18432);  // [128][72]
  f16* Tt = (f16*)shm;            // [128][136] aliases Qt/Kt after compute

  const int t = threadIdx.x, w = t>>6, l = t&63, lr = l&15, q = l>>4;
  const int b = blockIdx.z, n0 = blockIdx.y*128, m0 = blockIdx.x*128;
  const int wr = (w>>1)*64, wc = (w&1)*64;
  const float* Qb = Q  + ((size_t)b*2048 + n0)*64;
  const float* Kb = Km + ((size_t)b*2048 + m0)*64;

  const int sr = t>>3, sc = t&7;
#pragma unroll
  for (int j=0;j<4;++j){
    int row = sr + 32*j;
    const float* p  = Qb + (size_t)row*64 + sc*8;
    *(f16x8*)(Qt + row*72 + sc*8) = cvt_f16x8(*(const float4*)p, *(const float4*)(p+4));
    const float* pk = Kb + (size_t)row*64 + sc*8;
    *(f16x8*)(Kt + row*72 + sc*8) = cvt_f16x8(*(const float4*)pk, *(const float4*)(pk+4));
  }
  __syncthreads();

  f32x4 acc[4][4] = {};
#pragma unroll
  for (int kc=0;kc<2;++kc){
    f16x8 af[4], bf[4];
#pragma unroll
    for (int ti=0;ti<4;++ti) af[ti] = *(const f16x8*)(Qt + (wr+16*ti+lr)*72 + kc*32 + q*8);
#pragma unroll
    for (int tj=0;tj<4;++tj) bf[tj] = *(const f16x8*)(Kt + (wc+16*tj+lr)*72 + kc*32 + q*8);
#pragma unroll
    for (int ti=0;ti<4;++ti)
#pragma unroll
      for (int tj=0;tj<4;++tj)
        acc[ti][tj] = __builtin_amdgcn_mfma_f32_16x16x32_f16(af[ti], bf[tj], acc[ti][tj], 0,0,0);
  }
  __syncthreads();
#pragma unroll
  for (int ti=0;ti<4;++ti)
#pragma unroll
    for (int tj=0;tj<4;++tj)
#pragma unroll
      for (int r=0;r<4;++r)
        Tt[(wr+16*ti+4*q+r)*136 + wc+16*tj+lr] = (f16)(fmaxf(acc[ti][tj][r],0.f)*0.125f);
  __syncthreads();
  const int g16 = t&15, r0 = t>>4;
#pragma unroll
  for (int j=0;j<8;++j){
    int row = r0 + 16*j;
    *(f16x8*)(Ph + ((size_t)b*2048 + n0 + row)*2048 + m0 + g16*8) =
        *(const f16x8*)(Tt + row*136 + g16*8);
  }
}

// ---------------- kernel 2: split-j flash attention, barrier-free S-loop ---
// Grid 512 = 32 n-blocks x 8 batches x 2 j-halves; jh = bid&1 -> XCD parity
// so each j-half's 4 MB R slice is XCD-L2-resident.
// Per WG (256 thr, 4 waves): 64 Q-rows, j-half 1024 as 4 mt-tiles of 256.
// Main S-loop has NO LDS and NO barriers: A-frags (P) and B-frags (R) are
// global_load_dwordx4 direct into registers (16 rows x 64B contiguous per
// wave-instr = 16 cache lines, same as a coalesced load), double-buffered
// 2 chunks deep so vmcnt waits cover ~L2 latency. Barriers only in the 4
// softmax phases. LDS = El + stats = 36352 B.
__launch_bounds__(256, 2)
__global__ void k_attn(const f16* __restrict__ Ph, const f16* __restrict__ RhT,
                       const f16* __restrict__ VhT, float* __restrict__ Op,
                       float* __restrict__ mp, float* __restrict__ lp){
  __shared__ f16  El[64*264];
  __shared__ float stat_max[64*4];
  __shared__ float stat_sum[64*4];
  __shared__ float mrow[64];
  __shared__ float lrow[64];

  const int t = threadIdx.x, w = t>>6, l = t&63, lr = l&15, q = l>>4;
  const int bid = blockIdx.x;
  const int jh = bid & 1, nbb = bid >> 1, b = nbb & 7, nb = nbb >> 3;
  const int n0 = nb*64, jbase = jh*1024;
  const int wc = w*64;

  const f16* Pblk = Ph  + ((size_t)b*2048 + n0)*2048;
  const f16* Vb   = VhT + (size_t)b*64*2048;

  if (t < 64){ mrow[t] = -1e30f; lrow[t] = 0.0f; }

  f32x4 Oacc[4] = {};                           // O rows 16w..+15, cols 16tj+lr

  // A-frag base pointers (fixed across mt): P row (16ti+lr), k-offset q*8
  const f16* Ap[4];
#pragma unroll
  for (int ti=0;ti<4;++ti) Ap[ti] = Pblk + (size_t)(16*ti + lr)*2048 + q*8;

  for (int mt = 0; mt < 4; ++mt){
    const int jg = jbase + mt*256;
    f32x4 acc[4][4] = {};

    // B-frag base pointers for this j-tile: R^T row (jg+wc+16tj+lr)
    const f16* Bp[4];
#pragma unroll
    for (int tj=0;tj<4;++tj) Bp[tj] = RhT + (size_t)(jg + wc + 16*tj + lr)*2048 + q*8;

    // prime 2 chunks
    f16x8 afr[2][4], bfr[2][4];
#pragma unroll
    for (int s=0;s<2;++s){
#pragma unroll
      for (int ti=0;ti<4;++ti) afr[s][ti] = *(const f16x8*)(Ap[ti] + s*32);
#pragma unroll
      for (int tj=0;tj<4;++tj) bfr[s][tj] = *(const f16x8*)(Bp[tj] + s*32);
    }

#pragma unroll 8
    for (int kc = 0; kc < 64; ++kc){
      const int cur = kc & 1;
#pragma unroll
      for (int ti=0;ti<4;++ti)
#pragma unroll
        for (int tj=0;tj<4;++tj)
          acc[ti][tj] = __builtin_amdgcn_mfma_f32_16x16x32_f16(afr[cur][ti], bfr[cur][tj],
                                                               acc[ti][tj], 0,0,0);
      if (kc + 2 < 64){
#pragma unroll
        for (int ti=0;ti<4;++ti) afr[cur][ti] = *(const f16x8*)(Ap[ti] + (kc+2)*32);
#pragma unroll
        for (int tj=0;tj<4;++tj) bfr[cur][tj] = *(const f16x8*)(Bp[tj] + (kc+2)*32);
      }
    }

    // ---- online softmax ----
    float pm[4][4];
#pragma unroll
    for (int ti=0;ti<4;++ti)
#pragma unroll
      for (int r=0;r<4;++r)
        pm[ti][r] = fmaxf(fmaxf(acc[ti][0][r], acc[ti][1][r]),
                          fmaxf(acc[ti][2][r], acc[ti][3][r]));
#pragma unroll
    for (int mm=1;mm<16;mm<<=1)
#pragma unroll
      for (int ti=0;ti<4;++ti)
#pragma unroll
        for (int r=0;r<4;++r)
          pm[ti][r] = fmaxf(pm[ti][r], __shfl_xor(pm[ti][r], mm));
    if (lr == 0)
#pragma unroll
      for (int ti=0;ti<4;++ti)
#pragma unroll
        for (int r=0;r<4;++r)
          stat_max[(16*ti + 4*q + r)*4 + w] = pm[ti][r];
    __syncthreads();                            // B1: maxima visible; El reusable

    float Mn[4][4], ps[4][4], al[4];
#pragma unroll
    for (int ti=0;ti<4;++ti)
#pragma unroll
      for (int r=0;r<4;++r){
        int row = 16*ti + 4*q + r;
        float4 s4 = *(const float4*)&stat_max[row*4];
        float tm = fmaxf(fmaxf(s4.x,s4.y), fmaxf(s4.z,s4.w));
        float mo = mrow[row];
        float M  = fmaxf(mo, tm);
        Mn[ti][r] = M;
        ps[ti][r] = 0.f;
        if (ti == w) al[r] = __expf(mo - M);
      }
#pragma unroll
    for (int ti=0;ti<4;++ti)
#pragma unroll
      for (int tj=0;tj<4;++tj)
#pragma unroll
        for (int r=0;r<4;++r){
          float e = __expf(acc[ti][tj][r] - Mn[ti][r]);
          ps[ti][r] += e;
          El[(16*ti + 4*q + r)*264 + wc + 16*tj + lr] = (f16)e;
        }
#pragma unroll
    for (int mm=1;mm<16;mm<<=1)
#pragma unroll
      for (int ti=0;ti<4;++ti)
#pragma unroll
        for (int r=0;r<4;++r)
          ps[ti][r] += __shfl_xor(ps[ti][r], mm);
    if (lr == 0)
#pragma unroll
      for (int ti=0;ti<4;++ti)
#pragma unroll
        for (int r=0;r<4;++r)
          stat_sum[(16*ti + 4*q + r)*4 + w] = ps[ti][r];
#pragma unroll
    for (int r=0;r<4;++r)
#pragma unroll
      for (int tj=0;tj<4;++tj)
        Oacc[tj][r] *= al[r];                   // rescale running O
    __syncthreads();                            // B2: El + stat_sum visible

    if (t < 64){
      float m_o = mrow[t], tm = -1e30f, s4 = 0.f;
#pragma unroll
      for (int i=0;i<4;++i){ tm = fmaxf(tm, stat_max[t*4+i]); s4 += stat_sum[t*4+i]; }
      float M = fmaxf(m_o, tm);
      lrow[t] = lrow[t]*__expf(m_o - M) + s4;
      mrow[t] = M;
    }

    // ---- E @ V : O[16w..+15][64] += E[16 rows][256] * V[256][64]
    const f16* Ep = El + (16*w + lr)*264 + q*8;
    const f16* Vp = Vb + (size_t)lr*2048 + jg + q*8;
    f16x8 vb0[4];
#pragma unroll
    for (int tj=0;tj<4;++tj) vb0[tj] = *(const f16x8*)(Vp + tj*16*2048);
#pragma unroll
    for (int ks=0; ks<8; ++ks){
      f16x8 vn[4];
      if (ks < 7)
#pragma unroll
        for (int tj=0;tj<4;++tj) vn[tj] = *(const f16x8*)(Vp + tj*16*2048 + (ks+1)*32);
      f16x8 ae = *(const f16x8*)(Ep + ks*32);
#pragma unroll
      for (int tj=0;tj<4;++tj)
        Oacc[tj] = __builtin_amdgcn_mfma_f32_16x16x32_f16(ae, vb0[tj], Oacc[tj], 0,0,0);
#pragma unroll
      for (int tj=0;tj<4;++tj) vb0[tj] = vn[tj];
    }
  }

  __syncthreads();                              // final mrow/lrow visible
#pragma unroll
  for (int tj=0;tj<4;++tj)
#pragma unroll
    for (int r=0;r<4;++r){
      int row = 16*w + 4*q + r;
      int col = 16*tj + lr;
      Op[((size_t)bid*64 + row)*64 + col] = Oacc[tj][r];
    }
  if (t < 64){ mp[bid*64 + t] = mrow[t]; lp[bid*64 + t] = lrow[t]; }
}

// ---------------- kernel 3: combine the 2 j-half partials ------------------
__global__ void k_comb(const float* __restrict__ Op, const float* __restrict__ mp,
                       const float* __restrict__ lp, float* __restrict__ out){
  const int rb = blockIdx.x;                    // 0..255 = nb*8 + b
  const int b = rb & 7, nb = rb >> 3;
  const int bid0 = rb*2, bid1 = rb*2 + 1;
  const int t = threadIdx.x;
  const int rr = t >> 4, ci = t & 15;
#pragma unroll
  for (int i=0;i<4;++i){
    int row = rr + 16*i;
    float m0 = mp[bid0*64 + row], m1 = mp[bid1*64 + row];
    float l0 = lp[bid0*64 + row], l1 = lp[bid1*64 + row];
    float M = fmaxf(m0, m1);
    float a0 = __expf(m0 - M), a1 = __expf(m1 - M);
    float inv = 1.0f / (a0*l0 + a1*l1);
    float4 o0 = *(const float4*)&Op[((size_t)bid0*64 + row)*64 + ci*4];
    float4 o1 = *(const float4*)&Op[((size_t)bid1*64 + row)*64 + ci*4];
    float4 o;
    o.x = (a0*o0.x + a1*o1.x)*inv;
    o.y = (a0*o0.y + a1*o1.y)*inv;
    o.z = (a0*o0.z + a1*o1.z)*inv;
    o.w = (a0*o0.w + a1*o1.w)*inv;
    *(float4*)&out[((size_t)b*2048 + nb*64 + row)*64 + ci*4] = o;
  }
}

extern "C" void kernel_launch(void* const* d_in, const int* in_sizes, int n_in,
                              void* d_out, int out_size, void* d_ws, size_t ws_size,
                              hipStream_t stream){
  (void)in_sizes; (void)n_in; (void)out_size; (void)ws_size;
  const float* Q  = (const float*)d_in[0];
  const float* K  = (const float*)d_in[1];
  const float* V  = (const float*)d_in[2];
  const float* Dm = (const float*)d_in[3];
  float* out = (float*)d_out;
  char* ws = (char*)d_ws;
  f16* Ph  = (f16*)ws;                                   // 64 MB
  f16* RhT = (f16*)(ws + (size_t)64*1024*1024);          //  8 MB
  f16* VhT = (f16*)(ws + (size_t)72*1024*1024);          //  2 MB
  float* Op = (float*)(ws + (size_t)74*1024*1024);       //  8 MB
  float* mpp = (float*)(ws + (size_t)82*1024*1024);      // 128 KB
  float* lpp = (float*)(ws + (size_t)82*1024*1024 + 131072);

  k_rescaleT<<<dim3(32,32), 256, 0, stream>>>(Dm, RhT);
  k_vT      <<<dim3(32,8),  256, 0, stream>>>(V, VhT);
  k_qk      <<<dim3(16,16,8), 256, 0, stream>>>(Q, K, Ph);
  k_attn    <<<dim3(512),   256, 0, stream>>>(Ph, RhT, VhT, Op, mpp, lpp);
  k_comb    <<<dim3(256),   256, 0, stream>>>(Op, mpp, lpp, out);
}

// Round 6
// 260.117 us; speedup vs baseline: 2.1931x; 2.1931x over previous
//
#include <hip/hip_runtime.h>

// ScaledDotProductAttention: context = softmax(relu(Q K^T) @ R / 8) @ V
// B=8, N=2048, D=64. R = (1+e)/(1+exp(1-dist)), shared across batch.
//
// ws layout (needs >= 83 MB):
//   [0,   64MB)  Ph  : fp16 relu(QK^T)*0.125, [B][N][N]
//   [64MB,72MB)  RhT : fp16 R^T, [j][m]
//   [72MB,74MB)  VhT : fp16 V^T, [B][64][N]
//   [74MB,+8.4M) Op  : fp16 partial O, [512 wg][128][64]
//   then mp, lp : fp32 partial rowmax/rowsum, [512][128] each

typedef _Float16 f16;
typedef _Float16 f16x8 __attribute__((ext_vector_type(8)));
typedef float    f32x4 __attribute__((ext_vector_type(4)));

#define AS1C(p) ((const __attribute__((address_space(1))) void*)(p))
#define AS3(p)  ((__attribute__((address_space(3))) void*)(p))

__device__ __forceinline__ f16x8 cvt_f16x8(float4 a, float4 b){
  f16x8 v;
  v[0]=(f16)a.x; v[1]=(f16)a.y; v[2]=(f16)a.z; v[3]=(f16)a.w;
  v[4]=(f16)b.x; v[5]=(f16)b.y; v[6]=(f16)b.z; v[7]=(f16)b.w;
  return v;
}

// ---------------- kernel 0a: RhT[j][m] = rescale(dist[m][j]) in fp16 -------
__global__ void k_rescaleT(const float* __restrict__ Dm, f16* __restrict__ RhT){
  __shared__ f16 tl[64][65];
  const int k0 = blockIdx.x*64, m0 = blockIdx.y*64;
  const int t = threadIdx.x, c = t & 63, g = t >> 6;
#pragma unroll
  for (int i=0;i<16;++i){
    int k = g*16 + i;
    float d = Dm[(size_t)(k0 + k)*2048 + m0 + c];
    tl[k][c] = (f16)(3.7182818284590452f / (1.0f + __expf(1.0f - d)));
  }
  __syncthreads();
#pragma unroll
  for (int i=0;i<16;++i){
    int m = g*16 + i;
    RhT[(size_t)(m0 + m)*2048 + k0 + c] = tl[c][m];
  }
}

// ---------------- kernel 0b: VhT[b][d][m] = V[b][m][d] in fp16 -------------
__global__ void k_vT(const float* __restrict__ V, f16* __restrict__ VhT){
  __shared__ f16 tl[64][65];
  const int b = blockIdx.y, m0 = blockIdx.x*64;
  const int t = threadIdx.x, c = t & 63, g = t >> 6;
#pragma unroll
  for (int i=0;i<16;++i){
    int m = g*16 + i;
    tl[m][c] = (f16)V[((size_t)b*2048 + m0 + m)*64 + c];
  }
  __syncthreads();
#pragma unroll
  for (int i=0;i<16;++i){
    int d = g*16 + i;
    VhT[((size_t)b*64 + d)*2048 + m0 + c] = tl[c][d];
  }
}

// ---------------- kernel 1: Ph = relu(Q K^T) * 0.125 in fp16 ---------------
__launch_bounds__(256, 2)
__global__ void k_qk(const float* __restrict__ Q, const float* __restrict__ Km,
                     f16* __restrict__ Ph){
  __shared__ char shm[36864];
  f16* Qt = (f16*)shm;            // [128][72]
  f16* Kt = (f16*)(shm + 18432);  // [128][72]
  f16* Tt = (f16*)shm;            // [128][136] aliases Qt/Kt after compute

  const int t = threadIdx.x, w = t>>6, l = t&63, lr = l&15, q = l>>4;
  const int b = blockIdx.z, n0 = blockIdx.y*128, m0 = blockIdx.x*128;
  const int wr = (w>>1)*64, wc = (w&1)*64;
  const float* Qb = Q  + ((size_t)b*2048 + n0)*64;
  const float* Kb = Km + ((size_t)b*2048 + m0)*64;

  const int sr = t>>3, sc = t&7;
#pragma unroll
  for (int j=0;j<4;++j){
    int row = sr + 32*j;
    const float* p  = Qb + (size_t)row*64 + sc*8;
    *(f16x8*)(Qt + row*72 + sc*8) = cvt_f16x8(*(const float4*)p, *(const float4*)(p+4));
    const float* pk = Kb + (size_t)row*64 + sc*8;
    *(f16x8*)(Kt + row*72 + sc*8) = cvt_f16x8(*(const float4*)pk, *(const float4*)(pk+4));
  }
  __syncthreads();

  f32x4 acc[4][4] = {};
#pragma unroll
  for (int kc=0;kc<2;++kc){
    f16x8 af[4], bf[4];
#pragma unroll
    for (int ti=0;ti<4;++ti) af[ti] = *(const f16x8*)(Qt + (wr+16*ti+lr)*72 + kc*32 + q*8);
#pragma unroll
    for (int tj=0;tj<4;++tj) bf[tj] = *(const f16x8*)(Kt + (wc+16*tj+lr)*72 + kc*32 + q*8);
#pragma unroll
    for (int ti=0;ti<4;++ti)
#pragma unroll
      for (int tj=0;tj<4;++tj)
        acc[ti][tj] = __builtin_amdgcn_mfma_f32_16x16x32_f16(af[ti], bf[tj], acc[ti][tj], 0,0,0);
  }
  __syncthreads();
#pragma unroll
  for (int ti=0;ti<4;++ti)
#pragma unroll
    for (int tj=0;tj<4;++tj)
#pragma unroll
      for (int r=0;r<4;++r)
        Tt[(wr+16*ti+4*q+r)*136 + wc+16*tj+lr] = (f16)(fmaxf(acc[ti][tj][r],0.f)*0.125f);
  __syncthreads();
  const int g16 = t&15, r0 = t>>4;
#pragma unroll
  for (int j=0;j<8;++j){
    int row = r0 + 16*j;
    *(f16x8*)(Ph + ((size_t)b*2048 + n0 + row)*2048 + m0 + g16*8) =
        *(const f16x8*)(Tt + row*136 + g16*8);
  }
}

// ---------------- kernel 2: split-j flash attention over scores ------------
// Grid 512 = 16 n-blocks x 8 batches x 4 j-quarters; jq = bid&3 -> each XCD
// sees ONE 2 MB R-quarter (XCD-L2 resident).
// Per WG (256 thr, 4 waves): 128 Q-rows, j-quarter 512 as 2 mt-tiles of 256.
// Wave tile 128 x 64 (8x4 of 16x16x32) -> 42.7 FLOP per LDS-frag-byte (the
// round-3/4 structure was at the 32 FLOP/B LDS-read roofline).
// Per m-chunk(32): stage P 8K + R 16K via swizzled global_load_lds (dbuf).
// Softmax + E@V done in two 64-row passes; El (64x264 f16) ALIASES the
// staging buffers (live only between S-loop and pass end) -> LDS 54272 B
// -> 2 WGs/CU (8 waves, 2/SIMD).
__launch_bounds__(256, 2)
__global__ void k_attn(const f16* __restrict__ Ph, const f16* __restrict__ RhT,
                       const f16* __restrict__ VhT, f16* __restrict__ Op,
                       float* __restrict__ mp, float* __restrict__ lp){
  __shared__ char smem[54272];
  f16*  Pbuf = (f16*)smem;                      // [2][128][32] = 16384 B
  f16*  Rbuf = (f16*)(smem + 16384);            // [2][256][32] = 32768 B
  f16*  El   = (f16*)smem;                      // [64][264] = 33792 B (alias)
  float* stat_max = (float*)(smem + 49152);     // [128][4]
  float* stat_sum = (float*)(smem + 51200);     // [128][4]
  float* mrow = (float*)(smem + 53248);         // [128]
  float* lrow = (float*)(smem + 53760);         // [128]

  const int t = threadIdx.x, w = t>>6, l = t&63, lr = l&15, q = l>>4;
  const int bid = blockIdx.x;
  const int jq = bid & 3, nbb = bid >> 2, b = nbb & 7, nb = nbb >> 3;
  const int n0 = nb*128, jbase = jq*512;
  const int wc = w*64;                          // wave's S-col base

  const f16* Pblk = Ph  + ((size_t)b*2048 + n0)*2048;
  const f16* Vb   = VhT + (size_t)b*64*2048;

  if (t < 128){ mrow[t] = -1e30f; lrow[t] = 0.0f; }

  // Oacc[p][a][bb]: pass p rows 64p+32(w&1)+16a, cols 32(w>>1)+16bb
  f32x4 Oacc[2][2][2] = {};
  const int swz = (lr>>1)&3;                    // read-side XOR swizzle key

  auto stage = [&](int jg, int kc){
    const int cb = kc & 1, k0 = kc*32;
#pragma unroll
    for (int i=0;i<2;++i){                      // P: 128 rows x 32
      int slot = i*256 + t;
      int row = slot>>2, g = slot&3;
      int gs = (g ^ ((row>>1)&3))*8;
      __builtin_amdgcn_global_load_lds(AS1C(Pblk + (size_t)row*2048 + k0 + gs),
                                       AS3(Pbuf + cb*4096 + i*2048 + w*512), 16, 0, 0);
    }
#pragma unroll
    for (int i=0;i<4;++i){                      // R: 256 rows x 32
      int slot = i*256 + t;
      int row = slot>>2, g = slot&3;
      int gs = (g ^ ((row>>1)&3))*8;
      __builtin_amdgcn_global_load_lds(AS1C(RhT + (size_t)(jg + row)*2048 + k0 + gs),
                                       AS3(Rbuf + cb*8192 + i*2048 + w*512), 16, 0, 0);
    }
  };

  stage(jbase, 0);

  for (int mt = 0; mt < 2; ++mt){
    const int jg = jbase + mt*256;
    f32x4 acc[8][4] = {};

#pragma unroll 2
    for (int kc = 0; kc < 64; ++kc){
      __syncthreads();                          // chunk kc staged
      if (kc < 63) stage(jg, kc+1);
      const int cb = kc & 1;
      const f16* Pb = Pbuf + cb*4096;
      const f16* Rb = Rbuf + cb*8192;
      f16x8 bf[4];
#pragma unroll
      for (int tj=0;tj<4;++tj)
        bf[tj] = *(const f16x8*)(Rb + (wc + 16*tj + lr)*32 + (q ^ swz)*8);
#pragma unroll
      for (int ti=0;ti<8;++ti){
        f16x8 af = *(const f16x8*)(Pb + (16*ti + lr)*32 + (q ^ swz)*8);
#pragma unroll
        for (int tj=0;tj<4;++tj)
          acc[ti][tj] = __builtin_amdgcn_mfma_f32_16x16x32_f16(af, bf[tj], acc[ti][tj], 0,0,0);
      }
    }

    // ---- softmax + E@V in two 64-row passes (El aliases staging bufs) ----
#pragma unroll
    for (int p=0;p<2;++p){
      float pm[4][4];
#pragma unroll
      for (int ti=0;ti<4;++ti)
#pragma unroll
        for (int r=0;r<4;++r)
          pm[ti][r] = fmaxf(fmaxf(acc[4*p+ti][0][r], acc[4*p+ti][1][r]),
                            fmaxf(acc[4*p+ti][2][r], acc[4*p+ti][3][r]));
#pragma unroll
      for (int mm=1;mm<16;mm<<=1)
#pragma unroll
        for (int ti=0;ti<4;++ti)
#pragma unroll
          for (int r=0;r<4;++r)
            pm[ti][r] = fmaxf(pm[ti][r], __shfl_xor(pm[ti][r], mm));
      if (lr == 0)
#pragma unroll
        for (int ti=0;ti<4;++ti)
#pragma unroll
          for (int r=0;r<4;++r)
            stat_max[(64*p + 16*ti + 4*q + r)*4 + w] = pm[ti][r];
      __syncthreads();                          // B1: maxima visible; staging idle

      float Mn[4][4], ps[4][4], al[2][4];
#pragma unroll
      for (int ti=0;ti<4;++ti)
#pragma unroll
        for (int r=0;r<4;++r){
          int row = 64*p + 16*ti + 4*q + r;
          float4 s4 = *(const float4*)&stat_max[row*4];
          float tm = fmaxf(fmaxf(s4.x,s4.y), fmaxf(s4.z,s4.w));
          float mo = mrow[row];
          float M  = fmaxf(mo, tm);
          Mn[ti][r] = M;
          ps[ti][r] = 0.f;
          if ((ti>>1) == (w&1)) al[ti&1][r] = __expf(mo - M);
        }
#pragma unroll
      for (int ti=0;ti<4;++ti)
#pragma unroll
        for (int tj=0;tj<4;++tj)
#pragma unroll
          for (int r=0;r<4;++r){
            float e = __expf(acc[4*p+ti][tj][r] - Mn[ti][r]);
            ps[ti][r] += e;
            El[(16*ti + 4*q + r)*264 + wc + 16*tj + lr] = (f16)e;
          }
#pragma unroll
      for (int mm=1;mm<16;mm<<=1)
#pragma unroll
        for (int ti=0;ti<4;++ti)
#pragma unroll
          for (int r=0;r<4;++r)
            ps[ti][r] += __shfl_xor(ps[ti][r], mm);
      if (lr == 0)
#pragma unroll
        for (int ti=0;ti<4;++ti)
#pragma unroll
          for (int r=0;r<4;++r)
            stat_sum[(64*p + 16*ti + 4*q + r)*4 + w] = ps[ti][r];
#pragma unroll
      for (int a=0;a<2;++a)
#pragma unroll
        for (int bb=0;bb<2;++bb)
#pragma unroll
          for (int r=0;r<4;++r)
            Oacc[p][a][bb][r] *= al[a][r];      // rescale running O (pre-update mrow)
      __syncthreads();                          // B2: El + stat_sum visible

      if (t < 64){
        int row = 64*p + t;
        float m_o = mrow[row], tm = -1e30f, s4 = 0.f;
#pragma unroll
        for (int i=0;i<4;++i){ tm = fmaxf(tm, stat_max[row*4+i]); s4 += stat_sum[row*4+i]; }
        float M = fmaxf(m_o, tm);
        lrow[row] = lrow[row]*__expf(m_o - M) + s4;
        mrow[row] = M;
      }

      // ---- E @ V : O[pass rows][cols] += E[64][256] * V[256][64]
      const int erb = 32*(w&1), vcb = 32*(w>>1);
#pragma unroll
      for (int ks=0; ks<8; ++ks){
        f16x8 ae[2], bv[2];
#pragma unroll
        for (int a=0;a<2;++a)
          ae[a] = *(const f16x8*)(El + (erb + 16*a + lr)*264 + ks*32 + q*8);
#pragma unroll
        for (int bb=0;bb<2;++bb)
          bv[bb] = *(const f16x8*)(Vb + (size_t)(vcb + 16*bb + lr)*2048 + jg + ks*32 + q*8);
#pragma unroll
        for (int a=0;a<2;++a)
#pragma unroll
          for (int bb=0;bb<2;++bb)
            Oacc[p][a][bb] = __builtin_amdgcn_mfma_f32_16x16x32_f16(ae[a], bv[bb], Oacc[p][a][bb], 0,0,0);
      }
      __syncthreads();                          // B3: El reads done (pass1/restage safe)
    }

    if (mt == 0) stage(jbase + 256, 0);
  }

  __syncthreads();                              // final mrow/lrow visible
#pragma unroll
  for (int p=0;p<2;++p)
#pragma unroll
    for (int a=0;a<2;++a)
#pragma unroll
      for (int bb=0;bb<2;++bb)
#pragma unroll
        for (int r=0;r<4;++r){
          int row = 64*p + 32*(w&1) + 16*a + 4*q + r;
          int col = 32*(w>>1) + 16*bb + lr;
          Op[((size_t)bid*128 + row)*64 + col] = (f16)Oacc[p][a][bb][r];
        }
  if (t < 128){ mp[bid*128 + t] = mrow[t]; lp[bid*128 + t] = lrow[t]; }
}

// ---------------- kernel 3: combine the 4 j-quarter partials ---------------
__global__ void k_comb(const f16* __restrict__ Op, const float* __restrict__ mp,
                       const float* __restrict__ lp, float* __restrict__ out){
  const int rb = blockIdx.x;                    // 0..127 = nb*8 + b
  const int b = rb & 7, nb = rb >> 3;
  const int bid0 = rb*4;
  const int t = threadIdx.x;
  const int row = t >> 1, half = t & 1;

  float m_[4], a_[4];
  float M = -1e30f, den = 0.f;
#pragma unroll
  for (int i=0;i<4;++i){ m_[i] = mp[(bid0+i)*128 + row]; M = fmaxf(M, m_[i]); }
#pragma unroll
  for (int i=0;i<4;++i){ a_[i] = __expf(m_[i] - M); den += a_[i]*lp[(bid0+i)*128 + row]; }
  float inv = 1.0f / den;

#pragma unroll
  for (int g=0;g<4;++g){
    int c0 = half*32 + g*8;
    float o[8] = {};
#pragma unroll
    for (int i=0;i<4;++i){
      f16x8 v = *(const f16x8*)(Op + ((size_t)(bid0+i)*128 + row)*64 + c0);
#pragma unroll
      for (int e=0;e<8;++e) o[e] += a_[i]*(float)v[e];
    }
    float4 o0, o1;
    o0.x=o[0]*inv; o0.y=o[1]*inv; o0.z=o[2]*inv; o0.w=o[3]*inv;
    o1.x=o[4]*inv; o1.y=o[5]*inv; o1.z=o[6]*inv; o1.w=o[7]*inv;
    float* dst = out + ((size_t)b*2048 + nb*128 + row)*64 + c0;
    *(float4*)dst = o0;
    *(float4*)(dst+4) = o1;
  }
}

extern "C" void kernel_launch(void* const* d_in, const int* in_sizes, int n_in,
                              void* d_out, int out_size, void* d_ws, size_t ws_size,
                              hipStream_t stream){
  (void)in_sizes; (void)n_in; (void)out_size; (void)ws_size;
  const float* Q  = (const float*)d_in[0];
  const float* K  = (const float*)d_in[1];
  const float* V  = (const float*)d_in[2];
  const float* Dm = (const float*)d_in[3];
  float* out = (float*)d_out;
  char* ws = (char*)d_ws;
  f16* Ph  = (f16*)ws;                                   // 64 MB
  f16* RhT = (f16*)(ws + (size_t)64*1024*1024);          //  8 MB
  f16* VhT = (f16*)(ws + (size_t)72*1024*1024);          //  2 MB
  f16* Op  = (f16*)(ws + (size_t)74*1024*1024);          //  8.39 MB (512*128*64 f16)
  float* mpp = (float*)(ws + (size_t)74*1024*1024 + (size_t)512*128*64*2);
  float* lpp = mpp + 512*128;

  k_rescaleT<<<dim3(32,32), 256, 0, stream>>>(Dm, RhT);
  k_vT      <<<dim3(32,8),  256, 0, stream>>>(V, VhT);
  k_qk      <<<dim3(16,16,8), 256, 0, stream>>>(Q, K, Ph);
  k_attn    <<<dim3(512),   256, 0, stream>>>(Ph, RhT, VhT, Op, mpp, lpp);
  k_comb    <<<dim3(128),   256, 0, stream>>>(Op, mpp, lpp, out);
}